// Round 11
// baseline (751.999 us; speedup 1.0000x reference)
//
#include <hip/hip_runtime.h>

#define B_ 32
#define N_ 4096
#define M_ 32
#define F_ 256
#define A_ 8

typedef float f32x4 __attribute__((ext_vector_type(4)));
typedef int   i32x4 __attribute__((ext_vector_type(4)));

// workspace layout (floats):
//   [0, B*A*F)         anchor_feat (B,A,F)
//   [WS_E2, +B*A)      e2 = anchor_feat @ (a1-a2)
//   [WS_CNT]           producer-done counter (uint32), memset to 0 per call
#define WS_AF 0
#define WS_E2 (B_ * A_ * F_)
#define WS_CNT (WS_E2 + B_ * A_)

#define NBLK (B_ * (N_ / 64))  // 2048 blocks x 64 thr = 8 WG/CU -> co-resident by capacity

// e1 = h@(a1+a2) is provably irrelevant: e[b,n,k] = e1[b,n] + e2[b,k] and
// softmax over k is invariant to the per-row constant e1 (masked entries are
// -1e9 absolute; exp underflows to 0 either way; all-masked -> uniform 1/8).
// So fatoms is only read for the A=8 anchor rows per batch (producer stage).
__global__ __launch_bounds__(64) void fused_pc(const float* __restrict__ fatoms,
                                               const int* __restrict__ agraph,
                                               const int* __restrict__ anchor_idx,
                                               const float* __restrict__ W,
                                               const float* __restrict__ a,
                                               float* __restrict__ ws,
                                               unsigned* __restrict__ cnt,
                                               float* __restrict__ out) {
    int lane = threadIdx.x;
    __shared__ float smem[64 * A_];  // producer: xs[256]; consumer: attn[64][8]

    // ---------- producer: blocks 0..255 compute anchor_feat[bk] + e2[bk] ----------
    if (blockIdx.x < B_ * A_) {
        int bk = blockIdx.x;  // b*A_ + k
        int b  = bk >> 3;
        float* xs = smem;     // 256 floats
        int idx = anchor_idx[bk];
        *(f32x4*)(xs + lane * 4) =
            *(const f32x4*)(fatoms + ((size_t)b * N_ + idx) * F_ + lane * 4);
        __syncthreads();
        f32x4 acc0 = {0.f, 0.f, 0.f, 0.f}, acc1 = {0.f, 0.f, 0.f, 0.f};
        const float* wp = W + lane * 4;  // wave reads 1KB contiguous per W row
        for (int i = 0; i < F_; i += 4) {
            acc0 += xs[i + 0] * *(const f32x4*)(wp + (size_t)(i + 0) * F_);
            acc1 += xs[i + 1] * *(const f32x4*)(wp + (size_t)(i + 1) * F_);
            acc0 += xs[i + 2] * *(const f32x4*)(wp + (size_t)(i + 2) * F_);
            acc1 += xs[i + 3] * *(const f32x4*)(wp + (size_t)(i + 3) * F_);
        }
        f32x4 acc = acc0 + acc1;
        *(f32x4*)(ws + WS_AF + bk * F_ + lane * 4) = acc;
        f32x4 dd = *(const f32x4*)(a + lane * 4) - *(const f32x4*)(a + F_ + lane * 4);
        float part = acc.x * dd.x + acc.y * dd.y + acc.z * dd.z + acc.w * dd.w;
#pragma unroll
        for (int off = 32; off > 0; off >>= 1) part += __shfl_xor(part, off);
        if (lane == 0) ws[WS_E2 + bk] = part;
        // publish: every storing lane fences, then leader bumps the counter
        __threadfence();
        __syncthreads();
        if (lane == 0)
            __hip_atomic_fetch_add(cnt, 1u, __ATOMIC_RELEASE, __HIP_MEMORY_SCOPE_AGENT);
        __syncthreads();  // smem reused below
    }

    // ---------- consumer: all 2048 blocks; 64 rows each ----------
    int b    = blockIdx.x >> 6;
    int row0 = (blockIdx.x & 63) * 64;

    // producer-independent work first: agraph loads + anchor ids + mask
    const i32x4* gp = (const i32x4*)(agraph + ((size_t)b * N_ + row0 + lane) * M_);
    i32x4 g[M_ / 4];
#pragma unroll
    for (int j = 0; j < M_ / 4; ++j) g[j] = gp[j];

    int anch[A_];
#pragma unroll
    for (int k = 0; k < A_; ++k) anch[k] = anchor_idx[b * A_ + k];

    unsigned mk = 0;
#pragma unroll
    for (int j = 0; j < M_ / 4; ++j) {
#pragma unroll
        for (int k = 0; k < A_; ++k) {
            int hit = (g[j].x == anch[k]) | (g[j].y == anch[k]) |
                      (g[j].z == anch[k]) | (g[j].w == anch[k]);
            mk |= hit ? (1u << k) : 0u;
        }
    }

    // wait for all 256 producers (lane 0 spins; others sleep at the barrier)
    if (lane == 0) {
        while (__hip_atomic_load(cnt, __ATOMIC_ACQUIRE, __HIP_MEMORY_SCOPE_AGENT) <
               (unsigned)(B_ * A_)) {
            __builtin_amdgcn_s_sleep(1);
        }
    }
    __syncthreads();
    // per-lane acquire point so each lane's subsequent ws reads are ordered
    (void)__hip_atomic_load(cnt, __ATOMIC_ACQUIRE, __HIP_MEMORY_SCOPE_AGENT);

    const float* af = ws + WS_AF + b * (A_ * F_);
    float e2r[A_];
#pragma unroll
    for (int k = 0; k < A_; ++k) e2r[k] = ws[WS_E2 + b * A_ + k];
    float m8 = e2r[0];
#pragma unroll
    for (int k = 1; k < A_; ++k) m8 = fmaxf(m8, e2r[k]);
    float E[A_];
#pragma unroll
    for (int k = 0; k < A_; ++k) E[k] = __expf(e2r[k] - m8);

    f32x4 afr[A_];
#pragma unroll
    for (int k = 0; k < A_; ++k) afr[k] = *(const f32x4*)(af + k * F_ + lane * 4);

    {
        float p[A_], s = 0.f;
#pragma unroll
        for (int k = 0; k < A_; ++k) { p[k] = (mk & (1u << k)) ? E[k] : 0.f; s += p[k]; }
        if (mk == 0) {  // all masked -> uniform
#pragma unroll
            for (int k = 0; k < A_; ++k) p[k] = 1.f;
            s = 8.f;
        }
        float rinv = __builtin_amdgcn_rcpf(s);
        float (*attn_s)[A_] = (float (*)[A_])smem;
#pragma unroll
        for (int k = 0; k < A_; ++k) attn_s[lane][k] = p[k] * rinv;
    }
    __syncthreads();

    float (*attn_s)[A_] = (float (*)[A_])smem;
    size_t base = ((size_t)b * N_ + row0) * F_ + lane * 4;
    for (int r0 = 0; r0 < 64; r0 += 4) {
        f32x4 o[4];
#pragma unroll
        for (int u = 0; u < 4; ++u) {
            f32x4 pa = *(const f32x4*)&attn_s[r0 + u][0];  // broadcast reads
            f32x4 pb = *(const f32x4*)&attn_s[r0 + u][4];
            f32x4 t = pa.x * afr[0];
            t += pa.y * afr[1];
            t += pa.z * afr[2];
            t += pa.w * afr[3];
            t += pb.x * afr[4];
            t += pb.y * afr[5];
            t += pb.z * afr[6];
            t += pb.w * afr[7];
            o[u] = t;
        }
#pragma unroll
        for (int u = 0; u < 4; ++u)
            *(f32x4*)(out + base + (size_t)(r0 + u) * F_) = o[u];
    }
}

extern "C" void kernel_launch(void* const* d_in, const int* in_sizes, int n_in,
                              void* d_out, int out_size, void* d_ws, size_t ws_size,
                              hipStream_t stream) {
    const float* fatoms     = (const float*)d_in[0];
    const int*   agraph     = (const int*)d_in[1];
    const int*   anchor_idx = (const int*)d_in[2];
    const float* W          = (const float*)d_in[3];
    const float* a          = (const float*)d_in[4];
    float*       out        = (float*)d_out;
    float*       ws         = (float*)d_ws;
    unsigned*    cnt        = (unsigned*)(ws + WS_CNT);

    hipMemsetAsync(cnt, 0, sizeof(unsigned), stream);  // reset flag every call
    hipLaunchKernelGGL(fused_pc, dim3(NBLK), dim3(64), 0, stream,
                       fatoms, agraph, anchor_idx, W, a, ws, cnt, out);
}

// Round 12
// 51.853 us; speedup vs baseline: 14.5025x; 14.5025x over previous
//
#include <hip/hip_runtime.h>

#define B_ 32
#define N_ 4096
#define M_ 32
#define F_ 256
#define A_ 8

typedef float f32x4 __attribute__((ext_vector_type(4)));
typedef int   i32x4 __attribute__((ext_vector_type(4)));

// workspace layout (floats):
//   [0, B*A*F)        anchor_feat (B,A,F)
//   [WS_E2, +B*A)     e2 = anchor_feat @ (a1-a2)
#define WS_AF 0
#define WS_E2 (B_ * A_ * F_)

// ---- kernel 1: one block per batch; anchor_feat[b,:,:] + e2[b,:] -------
// e1 = h@(a1+a2) is provably irrelevant: e[b,n,k] = e1[b,n] + e2[b,k] and
// softmax over k is invariant to the per-row constant e1 (masked entries are
// -1e9 absolute; exp underflows to 0 either way; all-masked -> uniform 1/8).
// So fatoms is only read for the A=8 anchor rows per batch.
// Each W element is loaded ONCE per block and reused in 8 FMAs (8 indep chains).
__global__ __launch_bounds__(256) void anchor_kernel(const float* __restrict__ fatoms,
                                                     const int* __restrict__ anchor_idx,
                                                     const float* __restrict__ W,
                                                     const float* __restrict__ a,
                                                     float* __restrict__ ws) {
    int b    = blockIdx.x;
    int f    = threadIdx.x;
    int wave = f >> 6, lane = f & 63;
    __shared__ float xs[A_][F_];
    __shared__ float wred[4][A_];

    // stage the 8 anchor rows (coalesced 1KB per row)
#pragma unroll
    for (int k = 0; k < A_; ++k) {
        int idx = anchor_idx[b * A_ + k];
        xs[k][f] = fatoms[((size_t)b * N_ + idx) * F_ + f];
    }
    __syncthreads();

    // acc[k] = sum_i xs[k][i] * W[i][f] ; W element reused x8 from register
    float acc[A_] = {0.f, 0.f, 0.f, 0.f, 0.f, 0.f, 0.f, 0.f};
    for (int i = 0; i < F_; i += 2) {
        float w0 = W[(size_t)i * F_ + f];        // coalesced over f
        float w1 = W[(size_t)(i + 1) * F_ + f];
#pragma unroll
        for (int k = 0; k < A_; ++k) {
            acc[k] += xs[k][i] * w0;             // xs: LDS broadcast (free)
            acc[k] += xs[k][i + 1] * w1;
        }
    }

    float dd = a[f] - a[f + F_];
#pragma unroll
    for (int k = 0; k < A_; ++k) {
        ws[WS_AF + (b * A_ + k) * F_ + f] = acc[k];
        float part = acc[k] * dd;
#pragma unroll
        for (int off = 32; off > 0; off >>= 1) part += __shfl_xor(part, off);
        if (lane == 0) wred[wave][k] = part;
    }
    __syncthreads();
    if (f < A_)
        ws[WS_E2 + b * A_ + f] = (wred[0][f] + wred[1][f]) + (wred[2][f] + wred[3][f]);
}

// ---- kernel 2: main kernel — 1 wave per block, 64 rows (R8, unchanged) --
#define RPW 64

__global__ __launch_bounds__(64) void main_kernel(const int* __restrict__ agraph,
                                                  const int* __restrict__ anchor_idx,
                                                  const float* __restrict__ ws,
                                                  float* __restrict__ out) {
    int lane = threadIdx.x;
    const int chunks_per_batch = N_ / RPW;  // 64
    int b     = blockIdx.x / chunks_per_batch;
    int chunk = blockIdx.x % chunks_per_batch;
    int row0  = chunk * RPW;

    // critical-path agraph loads first (row = row0+lane)
    const i32x4* gp = (const i32x4*)(agraph + ((size_t)b * N_ + row0 + lane) * M_);
    i32x4 g[M_ / 4];
#pragma unroll
    for (int j = 0; j < M_ / 4; ++j) g[j] = gp[j];

    const float* af = ws + WS_AF + b * (A_ * F_);
    const float* e2 = ws + WS_E2 + b * A_;

    __shared__ float attn[RPW][A_];

    int   anch[A_];
    float e2r[A_];
#pragma unroll
    for (int k = 0; k < A_; ++k) {
        anch[k] = anchor_idx[b * A_ + k];
        e2r[k]  = e2[k];
    }
    // E_k = exp(e2_k - max_k e2)  (shared shift; masked-softmax ratios exact)
    float m8 = e2r[0];
#pragma unroll
    for (int k = 1; k < A_; ++k) m8 = fmaxf(m8, e2r[k]);
    float E[A_];
#pragma unroll
    for (int k = 0; k < A_; ++k) E[k] = __expf(e2r[k] - m8);

    f32x4 afr[A_];
#pragma unroll
    for (int k = 0; k < A_; ++k) afr[k] = *(const f32x4*)(af + k * F_ + lane * 4);

    // ---- phase 1: one row per lane (all 64 lanes) ----
    {
        unsigned mk = 0;
#pragma unroll
        for (int j = 0; j < M_ / 4; ++j) {
#pragma unroll
            for (int k = 0; k < A_; ++k) {
                int hit = (g[j].x == anch[k]) | (g[j].y == anch[k]) |
                          (g[j].z == anch[k]) | (g[j].w == anch[k]);
                mk |= hit ? (1u << k) : 0u;
            }
        }
        float p[A_], s = 0.f;
#pragma unroll
        for (int k = 0; k < A_; ++k) { p[k] = (mk & (1u << k)) ? E[k] : 0.f; s += p[k]; }
        if (mk == 0) {  // all masked -> uniform
#pragma unroll
            for (int k = 0; k < A_; ++k) p[k] = 1.f;
            s = 8.f;
        }
        float rinv = __builtin_amdgcn_rcpf(s);
#pragma unroll
        for (int k = 0; k < A_; ++k) attn[lane][k] = p[k] * rinv;
    }
    __syncthreads();  // single-wave block: cheap

    // ---- phase 2: wave writes its 64 rows (1KB/row), 4 rows in flight ----
    size_t base = ((size_t)b * N_ + row0) * F_ + lane * 4;
    for (int r0 = 0; r0 < RPW; r0 += 4) {
        f32x4 o[4];
#pragma unroll
        for (int u = 0; u < 4; ++u) {
            f32x4 pa = *(const f32x4*)&attn[r0 + u][0];  // broadcast reads
            f32x4 pb = *(const f32x4*)&attn[r0 + u][4];
            f32x4 t = pa.x * afr[0];
            t += pa.y * afr[1];
            t += pa.z * afr[2];
            t += pa.w * afr[3];
            t += pb.x * afr[4];
            t += pb.y * afr[5];
            t += pb.z * afr[6];
            t += pb.w * afr[7];
            o[u] = t;
        }
#pragma unroll
        for (int u = 0; u < 4; ++u)
            *(f32x4*)(out + base + (size_t)(r0 + u) * F_) = o[u];
    }
}

extern "C" void kernel_launch(void* const* d_in, const int* in_sizes, int n_in,
                              void* d_out, int out_size, void* d_ws, size_t ws_size,
                              hipStream_t stream) {
    const float* fatoms     = (const float*)d_in[0];
    const int*   agraph     = (const int*)d_in[1];
    const int*   anchor_idx = (const int*)d_in[2];
    const float* W          = (const float*)d_in[3];
    const float* a          = (const float*)d_in[4];
    float*       out        = (float*)d_out;
    float*       ws         = (float*)d_ws;

    hipLaunchKernelGGL(anchor_kernel, dim3(B_), dim3(256), 0, stream,
                       fatoms, anchor_idx, W, a, ws);
    hipLaunchKernelGGL(main_kernel, dim3(B_ * (N_ / RPW)), dim3(64), 0, stream,
                       agraph, anchor_idx, ws, out);
}